// Round 3
// baseline (323.527 us; speedup 1.0000x reference)
//
#include <hip/hip_runtime.h>
#include <math.h>

#define OVERLAP_THRESH 0.35f
#define VALID_THRESH   0.2f
#define NEGPOS         7
#define TMAX           64
#define NCHUNK         16   // prior chunks per (b,t) argmax
#define PPT            4    // priors per thread in match_loss
#define TPW            4    // targets per wave in best_prior

__device__ __forceinline__ float sl1(float x) {
    float ax = fabsf(x);
    return ax < 1.0f ? 0.5f * ax * ax : ax - 0.5f;
}
__device__ __forceinline__ float frcp(float x) { return __builtin_amdgcn_rcpf(x); }

// ---------------- K2: partial best-prior, split-K over priors, 4 targets/wave --------
// key = (iou_bits << 32) | (0xFFFFFFFF - p): max-key == argmax with lowest-p tie-break
__global__ void best_prior_partial_kernel(const float* __restrict__ priors,
                                          const float* __restrict__ targets,
                                          int P, int BT,
                                          unsigned long long* __restrict__ keys) {
    int wid  = blockIdx.x * (blockDim.x >> 6) + (threadIdx.x >> 6);
    int lane = threadIdx.x & 63;
    int ng    = (BT + TPW - 1) / TPW;       // target groups
    int group = wid % ng;
    int chunk = wid / ng;
    int bt0   = group * TPW;

    float tx1[TPW], ty1[TPW], tx2[TPW], ty2[TPW], ta[TPW];
    #pragma unroll
    for (int j = 0; j < TPW; j++) {
        int bt = min(bt0 + j, BT - 1);
        const float* tg = targets + (size_t)bt * 15;
        tx1[j] = tg[0]; ty1[j] = tg[1]; tx2[j] = tg[2]; ty2[j] = tg[3];
        ta[j]  = (tx2[j] - tx1[j]) * (ty2[j] - ty1[j]);
    }

    int cs = (P + NCHUNK - 1) / NCHUNK;
    int p0 = chunk * cs;
    int pend = min(p0 + cs, P);
    float best[TPW]; int bestp[TPW];
    #pragma unroll
    for (int j = 0; j < TPW; j++) { best[j] = -1.0f; bestp[j] = p0; }

    for (int p = p0 + lane; p < pend; p += 64) {
        float4 pr = ((const float4*)priors)[p];
        float hw = pr.z * 0.5f, hh = pr.w * 0.5f;
        float px1 = pr.x - hw, py1 = pr.y - hh;
        float px2 = pr.x + hw, py2 = pr.y + hh;
        float pa = (px2 - px1) * (py2 - py1);
        #pragma unroll
        for (int j = 0; j < TPW; j++) {
            float iw = fmaxf(fminf(tx2[j], px2) - fmaxf(tx1[j], px1), 0.0f);
            float ih = fmaxf(fminf(ty2[j], py2) - fmaxf(ty1[j], py1), 0.0f);
            float inter = iw * ih;
            float iou = inter * frcp(ta[j] + pa - inter);
            if (iou > best[j]) { best[j] = iou; bestp[j] = p; }  // strict >: lowest p/lane
        }
    }
    #pragma unroll
    for (int j = 0; j < TPW; j++) {
        unsigned long long key =
            ((unsigned long long)__float_as_uint(fmaxf(best[j], 0.0f)) << 32) |
            (unsigned long long)(0xFFFFFFFFu - (unsigned)bestp[j]);
        for (int off = 32; off; off >>= 1) {
            unsigned long long k2 = __shfl_down(key, off);
            if (k2 > key) key = k2;
        }
        if (lane == 0 && bt0 + j < BT) atomicMax(&keys[bt0 + j], key);
    }
}

// ---------------- K3: per-(b,p) match + per-prior losses, PPT priors/thread ----------
__global__ void match_loss_kernel(const float* __restrict__ priors,
                                  const float* __restrict__ targets,
                                  const float* __restrict__ loc_data,
                                  const float* __restrict__ conf_data,
                                  const float* __restrict__ landm_data,
                                  const unsigned long long* __restrict__ keys,
                                  int P, int T,
                                  float* __restrict__ rank_loss,
                                  int* __restrict__ num_pos,     // [B]
                                  int* __restrict__ total_pos1,  // [1]
                                  float* __restrict__ acc)       // [ll, llm, ce_pos, ce_neg]
{
    int b   = blockIdx.y;
    int tid = threadIdx.x;
    int p0  = (blockIdx.x * blockDim.x + tid) * PPT;

    __shared__ float4 s_td[TMAX];    // x1,y1,x2,y2
    __shared__ float2 s_aux[TMAX];   // area, label
    __shared__ int    s_ov[TMAX];    // (bpi<<1)|valid
    __shared__ int    s_av;
    __shared__ float  s_ll, s_llm, s_cep;
    __shared__ int    s_np, s_np1;

    if (tid == 0) { s_ll = 0.f; s_llm = 0.f; s_cep = 0.f; s_np = 0; s_np1 = 0; }
    int vflag = 0;
    if (tid < T) {
        const float* tg = targets + ((size_t)b * T + tid) * 15;
        float x1 = tg[0], y1 = tg[1], x2 = tg[2], y2 = tg[3];
        s_td[tid]  = make_float4(x1, y1, x2, y2);
        s_aux[tid] = make_float2((x2 - x1) * (y2 - y1), tg[14]);
        unsigned long long k = keys[b * T + tid];
        int bpi = (int)(0xFFFFFFFFu - (unsigned)(k & 0xFFFFFFFFull));
        float iou = __uint_as_float((unsigned)(k >> 32));
        vflag = (iou >= VALID_THRESH) ? 1 : 0;
        s_ov[tid] = (bpi << 1) | vflag;
    }
    unsigned long long vm = __ballot(vflag);     // wave 0 covers t=0..63
    if (tid == 0) s_av = (vm != 0ull) ? 1 : 0;
    __syncthreads();
    int av = s_av;

    float px1[PPT], py1[PPT], px2[PPT], py2[PPT], pa[PPT];
    float best[PPT]; int btidx[PPT], ovr[PPT], anyv[PPT];
    #pragma unroll
    for (int j = 0; j < PPT; j++) {
        int p = min(p0 + j, P - 1);
        float4 pr = ((const float4*)priors)[p];
        float hw = pr.z * 0.5f, hh = pr.w * 0.5f;
        px1[j] = pr.x - hw; py1[j] = pr.y - hh;
        px2[j] = pr.x + hw; py2[j] = pr.y + hh;
        pa[j]  = (px2[j] - px1[j]) * (py2[j] - py1[j]);
        best[j] = -1.0f; btidx[j] = 0; ovr[j] = -1; anyv[j] = 0;
    }

    for (int t = 0; t < T; t++) {
        float4 box = s_td[t];
        float2 aux = s_aux[t];
        int    ov  = s_ov[t];
        #pragma unroll
        for (int j = 0; j < PPT; j++) {
            float iw = fmaxf(fminf(box.z, px2[j]) - fmaxf(box.x, px1[j]), 0.0f);
            float ih = fmaxf(fminf(box.w, py2[j]) - fmaxf(box.y, py1[j]), 0.0f);
            float inter = iw * ih;
            float iou = inter * frcp(aux.x + pa[j] - inter);
            if (iou > best[j]) { best[j] = iou; btidx[j] = t; }   // first occurrence
            if ((ov >> 1) == p0 + j) { ovr[j] = t; anyv[j] |= (ov & 1); }
        }
    }

    float ll_s = 0.f, cep_s = 0.f, llm_s = 0.f;
    int np_s = 0, np1_s = 0;
    float rl[PPT];
    #pragma unroll
    for (int j = 0; j < PPT; j++) {
        int p = p0 + j;
        int bt = btidx[j];
        float bv = best[j];
        if (ovr[j] >= 0) bt = ovr[j];
        if (anyv[j])     bv = 2.0f;

        float lab  = s_aux[bt].y;
        float conf = (av && bv >= OVERLAP_THRESH) ? lab : 0.0f;
        int   ci   = (int)conf;
        bool  pos  = (ci != 0);
        bool  pos1 = (ci > 0);

        float c0 = 0.f, c1 = 0.f, ce = 0.f;
        if (p < P) {
            const float* cd = conf_data + ((size_t)b * P + p) * 2;
            c0 = cd[0]; c1 = cd[1];
            float mx = fmaxf(c0, c1);
            float lse = mx + __logf(1.0f + __expf(-fabsf(c0 - c1)));
            ce = lse - (pos ? c1 : c0);
        }
        rl[j] = (pos || p >= P) ? 0.0f : fmaxf(ce, 0.0f);

        if (p < P && pos) {
            float4 mb = s_td[bt];
            float pw = px2[j] - px1[j], ph = py2[j] - py1[j];
            float pcx = (px1[j] + px2[j]) * 0.5f, pcy = (py1[j] + py2[j]) * 0.5f;
            float gx = ((mb.x + mb.z) * 0.5f - pcx) * frcp(0.1f * pw);
            float gy = ((mb.y + mb.w) * 0.5f - pcy) * frcp(0.1f * ph);
            float gw = __logf((mb.z - mb.x) * frcp(pw)) * 5.0f;   // /0.2
            float gh = __logf((mb.w - mb.y) * frcp(ph)) * 5.0f;
            const float* ld = loc_data + ((size_t)b * P + p) * 4;
            ll_s += sl1(ld[0] - gx) + sl1(ld[1] - gy) + sl1(ld[2] - gw) + sl1(ld[3] - gh);
            cep_s += ce;
            np_s++;
        }
        if (p < P && pos1) {
            const float* lmd = landm_data + ((size_t)b * P + p) * 10;
            const float* lm  = targets + ((size_t)b * T + bt) * 15 + 4;
            float pw = px2[j] - px1[j], ph = py2[j] - py1[j];
            float pcx = (px1[j] + px2[j]) * 0.5f, pcy = (py1[j] + py2[j]) * 0.5f;
            float sx = frcp(0.1f * pw), sy = frcp(0.1f * ph);
            float s = 0.0f;
            #pragma unroll
            for (int k = 0; k < 5; k++) {
                float gx = (lm[2 * k]     - pcx) * sx;
                float gy = (lm[2 * k + 1] - pcy) * sy;
                s += sl1(lmd[2 * k] - gx) + sl1(lmd[2 * k + 1] - gy);
            }
            llm_s += s;
            np1_s++;
        }
    }
    if (p0 + PPT <= P) {
        *(float4*)&rank_loss[(size_t)b * P + p0] = make_float4(rl[0], rl[1], rl[2], rl[3]);
    } else {
        for (int j = 0; j < PPT; j++)
            if (p0 + j < P) rank_loss[(size_t)b * P + p0 + j] = rl[j];
    }

    if (np_s)  { atomicAdd(&s_ll, ll_s); atomicAdd(&s_cep, cep_s); atomicAdd(&s_np, np_s); }
    if (np1_s) { atomicAdd(&s_llm, llm_s); atomicAdd(&s_np1, np1_s); }
    __syncthreads();
    if (tid == 0) {
        if (s_np)  { atomicAdd(&num_pos[b], s_np); atomicAdd(&acc[0], s_ll); atomicAdd(&acc[2], s_cep); }
        if (s_np1) { atomicAdd(total_pos1, s_np1); atomicAdd(&acc[1], s_llm); }
    }
}

// ---------------- K4: per-batch exact sum of top-K rank_loss via radix select --------
// Fused value-sums: answer = sum(upper buckets across passes) + r_final * tau
__global__ void topk_kernel(const float* __restrict__ rank_loss,
                            const int* __restrict__ num_pos,
                            int P, float* __restrict__ acc) {
    int b = blockIdx.x;
    int tid = threadIdx.x;
    long long Kll = (long long)num_pos[b] * NEGPOS;
    int K = (Kll > P - 1) ? (P - 1) : (int)Kll;
    if (K <= 0) return;

    __shared__ int      hist[256];
    __shared__ float    vsum[256];
    __shared__ unsigned s_prefix;
    __shared__ int      s_r;
    __shared__ float    s_S;

    const float4* v4 = (const float4*)(rank_loss + (size_t)b * P);
    int n4 = P >> 2;
    if (tid == 0) { s_prefix = 0u; s_r = K; s_S = 0.f; }
    __syncthreads();

    for (int shift = 24; shift >= 0; shift -= 8) {
        if (tid < 256) { hist[tid] = 0; vsum[tid] = 0.f; }
        __syncthreads();
        unsigned prefix = s_prefix;
        unsigned hm = (shift == 24) ? 0u : (0xFFFFFFFFu << (shift + 8));
        for (int i = tid; i < n4; i += blockDim.x) {
            float4 x = v4[i];
            float xs[4] = {x.x, x.y, x.z, x.w};
            #pragma unroll
            for (int k = 0; k < 4; k++) {
                unsigned u = __float_as_uint(xs[k]);
                if ((u & hm) == prefix) {
                    int d = (u >> shift) & 255;
                    atomicAdd(&hist[d], 1);
                    atomicAdd(&vsum[d], xs[k]);
                }
            }
        }
        __syncthreads();
        if (tid == 0) {
            int r = s_r, cum = 0, d;
            float S = s_S;
            for (d = 255; d >= 0; d--) {
                int c = hist[d];
                if (cum + c >= r) break;
                cum += c;
                S += vsum[d];
            }
            if (d < 0) d = 0;
            s_prefix = prefix | ((unsigned)d << shift);
            s_r = r - cum;
            s_S = S;
        }
        __syncthreads();
    }
    if (tid == 0) {
        float tau = __uint_as_float(s_prefix);
        atomicAdd(&acc[3], s_S + (float)s_r * tau);
    }
}

// ---------------- K5: finalize -------------------------------------------------------
__global__ void finalize_kernel(const int* __restrict__ num_pos,
                                const int* __restrict__ total_pos1,
                                const float* __restrict__ acc,
                                int B, float* __restrict__ out) {
    int tp = 0;
    for (int b = 0; b < B; b++) tp += num_pos[b];
    float N  = fmaxf((float)tp, 1.0f);
    float N1 = fmaxf((float)(*total_pos1), 1.0f);
    out[0] = acc[0] / N;                 // loss_l / N
    out[1] = (acc[2] + acc[3]) / N;      // loss_c / N
    out[2] = acc[1] / N1;                // loss_landm / N1
}

extern "C" void kernel_launch(void* const* d_in, const int* in_sizes, int n_in,
                              void* d_out, int out_size, void* d_ws, size_t ws_size,
                              hipStream_t stream) {
    const float* loc_data   = (const float*)d_in[0];
    const float* conf_data  = (const float*)d_in[1];
    const float* landm_data = (const float*)d_in[2];
    const float* priors     = (const float*)d_in[3];
    const float* targets    = (const float*)d_in[4];
    float* out = (float*)d_out;

    int P  = in_sizes[3] / 4;
    int BP = in_sizes[0] / 4;
    int B  = BP / P;
    int T  = in_sizes[4] / (B * 15);
    int BT = B * T;

    char* ws = (char*)d_ws;
    float* rank_loss = (float*)ws;
    size_t off = (size_t)B * P * sizeof(float);
    // zeroed region starts here
    unsigned long long* keys = (unsigned long long*)(ws + off); off += (size_t)BT * sizeof(unsigned long long);
    int* num_pos    = (int*)(ws + off); off += (size_t)B * sizeof(int);
    int* total_pos1 = (int*)(ws + off); off += sizeof(int);
    float* acc      = (float*)(ws + off); off += 4 * sizeof(float);

    size_t zbytes = (size_t)((char*)(acc + 4) - (char*)keys);
    hipMemsetAsync(keys, 0, zbytes, stream);

    // K2: split-K best-prior, 4 targets per wave.
    int waves   = NCHUNK * ((BT + TPW - 1) / TPW);
    int blocks2 = (waves + 3) / 4;
    best_prior_partial_kernel<<<blocks2, 256, 0, stream>>>(priors, targets, P, BT, keys);

    // K3: match + per-prior losses, PPT priors/thread.
    dim3 g3((P + 256 * PPT - 1) / (256 * PPT), B);
    match_loss_kernel<<<g3, 256, 0, stream>>>(priors, targets, loc_data, conf_data,
                                              landm_data, keys, P, T,
                                              rank_loss, num_pos, total_pos1, acc);

    topk_kernel<<<B, 1024, 0, stream>>>(rank_loss, num_pos, P, acc);

    finalize_kernel<<<1, 1, 0, stream>>>(num_pos, total_pos1, acc, B, out);
}

// Round 4
// 173.320 us; speedup vs baseline: 1.8666x; 1.8666x over previous
//
#include <hip/hip_runtime.h>
#include <math.h>

#define OVERLAP_THRESH 0.35f
#define VALID_THRESH   0.2f
#define NEGPOS         7
#define TMAX           64
#define NCHUNK         16   // prior chunks per (b,t) argmax
#define PPT            4    // priors per thread in match_loss
#define TPW            4    // targets per wave in best_prior

__device__ __forceinline__ float sl1(float x) {
    float ax = fabsf(x);
    return ax < 1.0f ? 0.5f * ax * ax : ax - 0.5f;
}
__device__ __forceinline__ float frcp(float x) { return __builtin_amdgcn_rcpf(x); }

// ---------------- K2: partial best-prior, split-K over priors, 4 targets/wave --------
// key = (iou_bits << 32) | (0xFFFFFFFF - p): max-key == argmax with lowest-p tie-break
__global__ void best_prior_partial_kernel(const float* __restrict__ priors,
                                          const float* __restrict__ targets,
                                          int P, int BT,
                                          unsigned long long* __restrict__ keys) {
    int wid  = blockIdx.x * (blockDim.x >> 6) + (threadIdx.x >> 6);
    int lane = threadIdx.x & 63;
    int ng    = (BT + TPW - 1) / TPW;       // target groups
    int group = wid % ng;
    int chunk = wid / ng;
    int bt0   = group * TPW;

    float tx1[TPW], ty1[TPW], tx2[TPW], ty2[TPW], ta[TPW];
    #pragma unroll
    for (int j = 0; j < TPW; j++) {
        int bt = min(bt0 + j, BT - 1);
        const float* tg = targets + (size_t)bt * 15;
        tx1[j] = tg[0]; ty1[j] = tg[1]; tx2[j] = tg[2]; ty2[j] = tg[3];
        ta[j]  = (tx2[j] - tx1[j]) * (ty2[j] - ty1[j]);
    }

    int cs = (P + NCHUNK - 1) / NCHUNK;
    int p0 = chunk * cs;
    int pend = min(p0 + cs, P);
    float best[TPW]; int bestp[TPW];
    #pragma unroll
    for (int j = 0; j < TPW; j++) { best[j] = -1.0f; bestp[j] = p0; }

    for (int p = p0 + lane; p < pend; p += 64) {
        float4 pr = ((const float4*)priors)[p];
        float hw = pr.z * 0.5f, hh = pr.w * 0.5f;
        float px1 = pr.x - hw, py1 = pr.y - hh;
        float px2 = pr.x + hw, py2 = pr.y + hh;
        float pa = (px2 - px1) * (py2 - py1);
        #pragma unroll
        for (int j = 0; j < TPW; j++) {
            float iw = fmaxf(fminf(tx2[j], px2) - fmaxf(tx1[j], px1), 0.0f);
            float ih = fmaxf(fminf(ty2[j], py2) - fmaxf(ty1[j], py1), 0.0f);
            float inter = iw * ih;
            float iou = inter * frcp(ta[j] + pa - inter);
            if (iou > best[j]) { best[j] = iou; bestp[j] = p; }  // strict >: lowest p/lane
        }
    }
    #pragma unroll
    for (int j = 0; j < TPW; j++) {
        unsigned long long key =
            ((unsigned long long)__float_as_uint(fmaxf(best[j], 0.0f)) << 32) |
            (unsigned long long)(0xFFFFFFFFu - (unsigned)bestp[j]);
        for (int off = 32; off; off >>= 1) {
            unsigned long long k2 = __shfl_down(key, off);
            if (k2 > key) key = k2;
        }
        if (lane == 0 && bt0 + j < BT) atomicMax(&keys[bt0 + j], key);
    }
}

// ---------------- K3: per-(b,p) match + per-prior losses, PPT priors/thread ----------
__global__ void match_loss_kernel(const float* __restrict__ priors,
                                  const float* __restrict__ targets,
                                  const float* __restrict__ loc_data,
                                  const float* __restrict__ conf_data,
                                  const float* __restrict__ landm_data,
                                  const unsigned long long* __restrict__ keys,
                                  int P, int T,
                                  float* __restrict__ rank_loss,
                                  int* __restrict__ num_pos,     // [B]
                                  int* __restrict__ total_pos1,  // [1]
                                  float* __restrict__ acc)       // [ll, llm, ce_pos, ce_neg]
{
    int b   = blockIdx.y;
    int tid = threadIdx.x;
    int p0  = (blockIdx.x * blockDim.x + tid) * PPT;

    __shared__ float4 s_td[TMAX];    // x1,y1,x2,y2
    __shared__ float2 s_aux[TMAX];   // area, label
    __shared__ int    s_ov[TMAX];    // (bpi<<1)|valid
    __shared__ int    s_av;
    __shared__ float  s_ll, s_llm, s_cep;
    __shared__ int    s_np, s_np1;

    if (tid == 0) { s_ll = 0.f; s_llm = 0.f; s_cep = 0.f; s_np = 0; s_np1 = 0; }
    int vflag = 0;
    if (tid < T) {
        const float* tg = targets + ((size_t)b * T + tid) * 15;
        float x1 = tg[0], y1 = tg[1], x2 = tg[2], y2 = tg[3];
        s_td[tid]  = make_float4(x1, y1, x2, y2);
        s_aux[tid] = make_float2((x2 - x1) * (y2 - y1), tg[14]);
        unsigned long long k = keys[b * T + tid];
        int bpi = (int)(0xFFFFFFFFu - (unsigned)(k & 0xFFFFFFFFull));
        float iou = __uint_as_float((unsigned)(k >> 32));
        vflag = (iou >= VALID_THRESH) ? 1 : 0;
        s_ov[tid] = (bpi << 1) | vflag;
    }
    unsigned long long vm = __ballot(vflag);     // wave 0 covers t=0..63
    if (tid == 0) s_av = (vm != 0ull) ? 1 : 0;
    __syncthreads();
    int av = s_av;

    float px1[PPT], py1[PPT], px2[PPT], py2[PPT], pa[PPT];
    float best[PPT]; int btidx[PPT], ovr[PPT], anyv[PPT];
    #pragma unroll
    for (int j = 0; j < PPT; j++) {
        int p = min(p0 + j, P - 1);
        float4 pr = ((const float4*)priors)[p];
        float hw = pr.z * 0.5f, hh = pr.w * 0.5f;
        px1[j] = pr.x - hw; py1[j] = pr.y - hh;
        px2[j] = pr.x + hw; py2[j] = pr.y + hh;
        pa[j]  = (px2[j] - px1[j]) * (py2[j] - py1[j]);
        best[j] = -1.0f; btidx[j] = 0; ovr[j] = -1; anyv[j] = 0;
    }

    for (int t = 0; t < T; t++) {
        float4 box = s_td[t];
        float2 aux = s_aux[t];
        int    ov  = s_ov[t];
        #pragma unroll
        for (int j = 0; j < PPT; j++) {
            float iw = fmaxf(fminf(box.z, px2[j]) - fmaxf(box.x, px1[j]), 0.0f);
            float ih = fmaxf(fminf(box.w, py2[j]) - fmaxf(box.y, py1[j]), 0.0f);
            float inter = iw * ih;
            float iou = inter * frcp(aux.x + pa[j] - inter);
            if (iou > best[j]) { best[j] = iou; btidx[j] = t; }   // first occurrence
            if ((ov >> 1) == p0 + j) { ovr[j] = t; anyv[j] |= (ov & 1); }
        }
    }

    float ll_s = 0.f, cep_s = 0.f, llm_s = 0.f;
    int np_s = 0, np1_s = 0;
    float rl[PPT];
    #pragma unroll
    for (int j = 0; j < PPT; j++) {
        int p = p0 + j;
        int bt = btidx[j];
        float bv = best[j];
        if (ovr[j] >= 0) bt = ovr[j];
        if (anyv[j])     bv = 2.0f;

        float lab  = s_aux[bt].y;
        float conf = (av && bv >= OVERLAP_THRESH) ? lab : 0.0f;
        int   ci   = (int)conf;
        bool  pos  = (ci != 0);
        bool  pos1 = (ci > 0);

        float c0 = 0.f, c1 = 0.f, ce = 0.f;
        if (p < P) {
            const float* cd = conf_data + ((size_t)b * P + p) * 2;
            c0 = cd[0]; c1 = cd[1];
            float mx = fmaxf(c0, c1);
            float lse = mx + __logf(1.0f + __expf(-fabsf(c0 - c1)));
            ce = lse - (pos ? c1 : c0);
        }
        rl[j] = (pos || p >= P) ? 0.0f : fmaxf(ce, 0.0f);

        if (p < P && pos) {
            float4 mb = s_td[bt];
            float pw = px2[j] - px1[j], ph = py2[j] - py1[j];
            float pcx = (px1[j] + px2[j]) * 0.5f, pcy = (py1[j] + py2[j]) * 0.5f;
            float gx = ((mb.x + mb.z) * 0.5f - pcx) * frcp(0.1f * pw);
            float gy = ((mb.y + mb.w) * 0.5f - pcy) * frcp(0.1f * ph);
            float gw = __logf((mb.z - mb.x) * frcp(pw)) * 5.0f;   // /0.2
            float gh = __logf((mb.w - mb.y) * frcp(ph)) * 5.0f;
            const float* ld = loc_data + ((size_t)b * P + p) * 4;
            ll_s += sl1(ld[0] - gx) + sl1(ld[1] - gy) + sl1(ld[2] - gw) + sl1(ld[3] - gh);
            cep_s += ce;
            np_s++;
        }
        if (p < P && pos1) {
            const float* lmd = landm_data + ((size_t)b * P + p) * 10;
            const float* lm  = targets + ((size_t)b * T + bt) * 15 + 4;
            float pw = px2[j] - px1[j], ph = py2[j] - py1[j];
            float pcx = (px1[j] + px2[j]) * 0.5f, pcy = (py1[j] + py2[j]) * 0.5f;
            float sx = frcp(0.1f * pw), sy = frcp(0.1f * ph);
            float s = 0.0f;
            #pragma unroll
            for (int k = 0; k < 5; k++) {
                float gx = (lm[2 * k]     - pcx) * sx;
                float gy = (lm[2 * k + 1] - pcy) * sy;
                s += sl1(lmd[2 * k] - gx) + sl1(lmd[2 * k + 1] - gy);
            }
            llm_s += s;
            np1_s++;
        }
    }
    if (p0 + PPT <= P) {
        *(float4*)&rank_loss[(size_t)b * P + p0] = make_float4(rl[0], rl[1], rl[2], rl[3]);
    } else {
        for (int j = 0; j < PPT; j++)
            if (p0 + j < P) rank_loss[(size_t)b * P + p0 + j] = rl[j];
    }

    if (np_s)  { atomicAdd(&s_ll, ll_s); atomicAdd(&s_cep, cep_s); atomicAdd(&s_np, np_s); }
    if (np1_s) { atomicAdd(&s_llm, llm_s); atomicAdd(&s_np1, np1_s); }
    __syncthreads();
    if (tid == 0) {
        if (s_np)  { atomicAdd(&num_pos[b], s_np); atomicAdd(&acc[0], s_ll); atomicAdd(&acc[2], s_cep); }
        if (s_np1) { atomicAdd(total_pos1, s_np1); atomicAdd(&acc[1], s_llm); }
    }
}

// ---------------- K4: per-batch exact sum of top-K rank_loss via radix select --------
// Ballot-aggregated histograms (1 atomic per same-digit group per wave) +
// parallel suffix-sum digit selection. Final scan sums x > tau.
__global__ void topk_kernel(const float* __restrict__ rank_loss,
                            const int* __restrict__ num_pos,
                            int P, float* __restrict__ acc) {
    int b    = blockIdx.x;
    int tid  = threadIdx.x;
    int lane = tid & 63;
    long long Kll = (long long)num_pos[b] * NEGPOS;
    int K = (Kll > P - 1) ? (P - 1) : (int)Kll;
    if (K <= 0) return;

    __shared__ int      hist[256];
    __shared__ int      sfx[256];
    __shared__ unsigned s_prefix;
    __shared__ int      s_r;
    __shared__ float    s_sum[16];
    __shared__ int      s_cnt[16];

    const float4* v4 = (const float4*)(rank_loss + (size_t)b * P);
    int n4 = P >> 2;
    if (tid == 0) { s_prefix = 0u; s_r = K; }
    __syncthreads();

    for (int shift = 24; shift >= 0; shift -= 8) {
        if (tid < 256) hist[tid] = 0;
        __syncthreads();
        unsigned prefix = s_prefix;
        unsigned hm = (shift == 24) ? 0u : (0xFFFFFFFFu << (shift + 8));
        for (int i = tid; i < n4; i += blockDim.x) {
            float4 x = v4[i];
            float xs[4] = {x.x, x.y, x.z, x.w};
            #pragma unroll
            for (int k = 0; k < 4; k++) {
                unsigned u  = __float_as_uint(xs[k]);
                bool     ok = ((u & hm) == prefix);
                unsigned d  = (u >> shift) & 255u;
                // group lanes by digit: 1 participation ballot + 8 bit ballots
                unsigned long long m = __ballot(ok);
                #pragma unroll
                for (int bit = 0; bit < 8; bit++) {
                    unsigned long long bb = __ballot((d >> bit) & 1u);
                    m &= ((d >> bit) & 1u) ? bb : ~bb;
                }
                if (ok && lane == (__ffsll((long long)m) - 1))
                    atomicAdd(&hist[d], __popcll(m));
            }
        }
        __syncthreads();
        // parallel suffix sum: sfx[d] = count of elements with digit >= d
        if (tid < 256) sfx[tid] = hist[tid];
        __syncthreads();
        for (int off = 1; off < 256; off <<= 1) {
            int v = 0;
            if (tid < 256) { v = sfx[tid]; if (tid + off < 256) v += sfx[tid + off]; }
            __syncthreads();
            if (tid < 256) sfx[tid] = v;
            __syncthreads();
        }
        int r = s_r;
        __syncthreads();
        if (tid < 256) {
            int ge  = sfx[tid];
            int ge1 = (tid == 255) ? 0 : sfx[tid + 1];
            if (ge >= r && ge1 < r) {          // unique winning digit
                s_prefix = prefix | ((unsigned)tid << shift);
                s_r = r - ge1;                 // rank within this digit's bucket
            }
        }
        __syncthreads();
    }
    float tau = __uint_as_float(s_prefix);
    int   r   = s_r;

    // final scan: sum and count of values strictly above tau
    float sum = 0.0f; int cnt = 0;
    for (int i = tid; i < n4; i += blockDim.x) {
        float4 x = v4[i];
        if (x.x > tau) { sum += x.x; cnt++; }
        if (x.y > tau) { sum += x.y; cnt++; }
        if (x.z > tau) { sum += x.z; cnt++; }
        if (x.w > tau) { sum += x.w; cnt++; }
    }
    for (int off = 32; off; off >>= 1) {
        sum += __shfl_down(sum, off);
        cnt += __shfl_down(cnt, off);
    }
    int wv = tid >> 6;
    if (lane == 0) { s_sum[wv] = sum; s_cnt[wv] = cnt; }
    __syncthreads();
    if (tid == 0) {
        float st = 0.f; int ct = 0;
        int nw = blockDim.x >> 6;
        for (int i = 0; i < nw; i++) { st += s_sum[i]; ct += s_cnt[i]; }
        atomicAdd(&acc[3], st + (float)(K - ct) * tau);
    }
}

// ---------------- K5: finalize -------------------------------------------------------
__global__ void finalize_kernel(const int* __restrict__ num_pos,
                                const int* __restrict__ total_pos1,
                                const float* __restrict__ acc,
                                int B, float* __restrict__ out) {
    int tp = 0;
    for (int b = 0; b < B; b++) tp += num_pos[b];
    float N  = fmaxf((float)tp, 1.0f);
    float N1 = fmaxf((float)(*total_pos1), 1.0f);
    out[0] = acc[0] / N;                 // loss_l / N
    out[1] = (acc[2] + acc[3]) / N;      // loss_c / N
    out[2] = acc[1] / N1;                // loss_landm / N1
}

extern "C" void kernel_launch(void* const* d_in, const int* in_sizes, int n_in,
                              void* d_out, int out_size, void* d_ws, size_t ws_size,
                              hipStream_t stream) {
    const float* loc_data   = (const float*)d_in[0];
    const float* conf_data  = (const float*)d_in[1];
    const float* landm_data = (const float*)d_in[2];
    const float* priors     = (const float*)d_in[3];
    const float* targets    = (const float*)d_in[4];
    float* out = (float*)d_out;

    int P  = in_sizes[3] / 4;
    int BP = in_sizes[0] / 4;
    int B  = BP / P;
    int T  = in_sizes[4] / (B * 15);
    int BT = B * T;

    char* ws = (char*)d_ws;
    float* rank_loss = (float*)ws;
    size_t off = (size_t)B * P * sizeof(float);
    // zeroed region starts here
    unsigned long long* keys = (unsigned long long*)(ws + off); off += (size_t)BT * sizeof(unsigned long long);
    int* num_pos    = (int*)(ws + off); off += (size_t)B * sizeof(int);
    int* total_pos1 = (int*)(ws + off); off += sizeof(int);
    float* acc      = (float*)(ws + off); off += 4 * sizeof(float);

    size_t zbytes = (size_t)((char*)(acc + 4) - (char*)keys);
    hipMemsetAsync(keys, 0, zbytes, stream);

    // K2: split-K best-prior, 4 targets per wave.
    int waves   = NCHUNK * ((BT + TPW - 1) / TPW);
    int blocks2 = (waves + 3) / 4;
    best_prior_partial_kernel<<<blocks2, 256, 0, stream>>>(priors, targets, P, BT, keys);

    // K3: match + per-prior losses, PPT priors/thread.
    dim3 g3((P + 256 * PPT - 1) / (256 * PPT), B);
    match_loss_kernel<<<g3, 256, 0, stream>>>(priors, targets, loc_data, conf_data,
                                              landm_data, keys, P, T,
                                              rank_loss, num_pos, total_pos1, acc);

    topk_kernel<<<B, 1024, 0, stream>>>(rank_loss, num_pos, P, acc);

    finalize_kernel<<<1, 1, 0, stream>>>(num_pos, total_pos1, acc, B, out);
}

// Round 5
// 137.030 us; speedup vs baseline: 2.3610x; 1.2648x over previous
//
#include <hip/hip_runtime.h>
#include <math.h>

#define OVERLAP_THRESH 0.35f
#define VALID_THRESH   0.2f
#define NEGPOS         7
#define TMAX           64
#define NCHUNK         16   // prior chunks per (b,t) argmax
#define PPT            4    // priors per thread in match_loss
#define TPW            4    // targets per wave in best_prior
#define HB             2048 // 11-bit coarse histogram buckets (u >> 20, sign bit 0)
#define CAP            12288 // LDS compact-list capacity (48 KB)

__device__ __forceinline__ float sl1(float x) {
    float ax = fabsf(x);
    return ax < 1.0f ? 0.5f * ax * ax : ax - 0.5f;
}
__device__ __forceinline__ float frcp(float x) { return __builtin_amdgcn_rcpf(x); }

// ---------------- K2: partial best-prior, split-K over priors, 4 targets/wave --------
// key = (iou_bits << 32) | (0xFFFFFFFF - p): max-key == argmax with lowest-p tie-break
__global__ void best_prior_partial_kernel(const float* __restrict__ priors,
                                          const float* __restrict__ targets,
                                          int P, int BT,
                                          unsigned long long* __restrict__ keys) {
    int wid  = blockIdx.x * (blockDim.x >> 6) + (threadIdx.x >> 6);
    int lane = threadIdx.x & 63;
    int ng    = (BT + TPW - 1) / TPW;       // target groups
    int group = wid % ng;
    int chunk = wid / ng;
    int bt0   = group * TPW;

    float tx1[TPW], ty1[TPW], tx2[TPW], ty2[TPW], ta[TPW];
    #pragma unroll
    for (int j = 0; j < TPW; j++) {
        int bt = min(bt0 + j, BT - 1);
        const float* tg = targets + (size_t)bt * 15;
        tx1[j] = tg[0]; ty1[j] = tg[1]; tx2[j] = tg[2]; ty2[j] = tg[3];
        ta[j]  = (tx2[j] - tx1[j]) * (ty2[j] - ty1[j]);
    }

    int cs = (P + NCHUNK - 1) / NCHUNK;
    int p0 = chunk * cs;
    int pend = min(p0 + cs, P);
    float best[TPW]; int bestp[TPW];
    #pragma unroll
    for (int j = 0; j < TPW; j++) { best[j] = -1.0f; bestp[j] = p0; }

    for (int p = p0 + lane; p < pend; p += 64) {
        float4 pr = ((const float4*)priors)[p];
        float hw = pr.z * 0.5f, hh = pr.w * 0.5f;
        float px1 = pr.x - hw, py1 = pr.y - hh;
        float px2 = pr.x + hw, py2 = pr.y + hh;
        float pa = (px2 - px1) * (py2 - py1);
        #pragma unroll
        for (int j = 0; j < TPW; j++) {
            float iw = fmaxf(fminf(tx2[j], px2) - fmaxf(tx1[j], px1), 0.0f);
            float ih = fmaxf(fminf(ty2[j], py2) - fmaxf(ty1[j], py1), 0.0f);
            float inter = iw * ih;
            float iou = inter * frcp(ta[j] + pa - inter);
            if (iou > best[j]) { best[j] = iou; bestp[j] = p; }  // strict >: lowest p/lane
        }
    }
    #pragma unroll
    for (int j = 0; j < TPW; j++) {
        unsigned long long key =
            ((unsigned long long)__float_as_uint(fmaxf(best[j], 0.0f)) << 32) |
            (unsigned long long)(0xFFFFFFFFu - (unsigned)bestp[j]);
        for (int off = 32; off; off >>= 1) {
            unsigned long long k2 = __shfl_down(key, off);
            if (k2 > key) key = k2;
        }
        if (lane == 0 && bt0 + j < BT) atomicMax(&keys[bt0 + j], key);
    }
}

// ---------------- K3: per-(b,p) match + per-prior losses, PPT priors/thread ----------
// Also builds the 11-bit coarse histogram of rank_loss into ghist[b][HB].
__global__ void match_loss_kernel(const float* __restrict__ priors,
                                  const float* __restrict__ targets,
                                  const float* __restrict__ loc_data,
                                  const float* __restrict__ conf_data,
                                  const float* __restrict__ landm_data,
                                  const unsigned long long* __restrict__ keys,
                                  int P, int T,
                                  float* __restrict__ rank_loss,
                                  int* __restrict__ ghist,       // [B][HB]
                                  int* __restrict__ num_pos,     // [B]
                                  int* __restrict__ total_pos1,  // [1]
                                  float* __restrict__ acc)       // [ll, llm, ce_pos, ce_neg]
{
    int b   = blockIdx.y;
    int tid = threadIdx.x;
    int p0  = (blockIdx.x * blockDim.x + tid) * PPT;

    __shared__ float4 s_td[TMAX];    // x1,y1,x2,y2
    __shared__ float2 s_aux[TMAX];   // area, label
    __shared__ int    s_ov[TMAX];    // (bpi<<1)|valid
    __shared__ int    s_av;
    __shared__ float  s_ll, s_llm, s_cep;
    __shared__ int    s_np, s_np1;
    __shared__ int    s_hist[HB];

    if (tid == 0) { s_ll = 0.f; s_llm = 0.f; s_cep = 0.f; s_np = 0; s_np1 = 0; }
    for (int i = tid; i < HB; i += blockDim.x) s_hist[i] = 0;
    int vflag = 0;
    if (tid < T) {
        const float* tg = targets + ((size_t)b * T + tid) * 15;
        float x1 = tg[0], y1 = tg[1], x2 = tg[2], y2 = tg[3];
        s_td[tid]  = make_float4(x1, y1, x2, y2);
        s_aux[tid] = make_float2((x2 - x1) * (y2 - y1), tg[14]);
        unsigned long long k = keys[b * T + tid];
        int bpi = (int)(0xFFFFFFFFu - (unsigned)(k & 0xFFFFFFFFull));
        float iou = __uint_as_float((unsigned)(k >> 32));
        vflag = (iou >= VALID_THRESH) ? 1 : 0;
        s_ov[tid] = (bpi << 1) | vflag;
    }
    unsigned long long vm = __ballot(vflag);     // wave 0 covers t=0..63
    if (tid == 0) s_av = (vm != 0ull) ? 1 : 0;
    __syncthreads();
    int av = s_av;

    float px1[PPT], py1[PPT], px2[PPT], py2[PPT], pa[PPT];
    float best[PPT]; int btidx[PPT], ovr[PPT], anyv[PPT];
    #pragma unroll
    for (int j = 0; j < PPT; j++) {
        int p = min(p0 + j, P - 1);
        float4 pr = ((const float4*)priors)[p];
        float hw = pr.z * 0.5f, hh = pr.w * 0.5f;
        px1[j] = pr.x - hw; py1[j] = pr.y - hh;
        px2[j] = pr.x + hw; py2[j] = pr.y + hh;
        pa[j]  = (px2[j] - px1[j]) * (py2[j] - py1[j]);
        best[j] = -1.0f; btidx[j] = 0; ovr[j] = -1; anyv[j] = 0;
    }

    for (int t = 0; t < T; t++) {
        float4 box = s_td[t];
        float2 aux = s_aux[t];
        int    ov  = s_ov[t];
        #pragma unroll
        for (int j = 0; j < PPT; j++) {
            float iw = fmaxf(fminf(box.z, px2[j]) - fmaxf(box.x, px1[j]), 0.0f);
            float ih = fmaxf(fminf(box.w, py2[j]) - fmaxf(box.y, py1[j]), 0.0f);
            float inter = iw * ih;
            float iou = inter * frcp(aux.x + pa[j] - inter);
            if (iou > best[j]) { best[j] = iou; btidx[j] = t; }   // first occurrence
            if ((ov >> 1) == p0 + j) { ovr[j] = t; anyv[j] |= (ov & 1); }
        }
    }

    float ll_s = 0.f, cep_s = 0.f, llm_s = 0.f;
    int np_s = 0, np1_s = 0;
    float rl[PPT];
    #pragma unroll
    for (int j = 0; j < PPT; j++) {
        int p = p0 + j;
        int bt = btidx[j];
        float bv = best[j];
        if (ovr[j] >= 0) bt = ovr[j];
        if (anyv[j])     bv = 2.0f;

        float lab  = s_aux[bt].y;
        float conf = (av && bv >= OVERLAP_THRESH) ? lab : 0.0f;
        int   ci   = (int)conf;
        bool  pos  = (ci != 0);
        bool  pos1 = (ci > 0);

        float c0 = 0.f, c1 = 0.f, ce = 0.f;
        if (p < P) {
            const float* cd = conf_data + ((size_t)b * P + p) * 2;
            c0 = cd[0]; c1 = cd[1];
            float mx = fmaxf(c0, c1);
            float lse = mx + __logf(1.0f + __expf(-fabsf(c0 - c1)));
            ce = lse - (pos ? c1 : c0);
        }
        rl[j] = (pos || p >= P) ? 0.0f : fmaxf(ce, 0.0f);
        if (p < P) atomicAdd(&s_hist[__float_as_uint(rl[j]) >> 20], 1);

        if (p < P && pos) {
            float4 mb = s_td[bt];
            float pw = px2[j] - px1[j], ph = py2[j] - py1[j];
            float pcx = (px1[j] + px2[j]) * 0.5f, pcy = (py1[j] + py2[j]) * 0.5f;
            float gx = ((mb.x + mb.z) * 0.5f - pcx) * frcp(0.1f * pw);
            float gy = ((mb.y + mb.w) * 0.5f - pcy) * frcp(0.1f * ph);
            float gw = __logf((mb.z - mb.x) * frcp(pw)) * 5.0f;   // /0.2
            float gh = __logf((mb.w - mb.y) * frcp(ph)) * 5.0f;
            const float* ld = loc_data + ((size_t)b * P + p) * 4;
            ll_s += sl1(ld[0] - gx) + sl1(ld[1] - gy) + sl1(ld[2] - gw) + sl1(ld[3] - gh);
            cep_s += ce;
            np_s++;
        }
        if (p < P && pos1) {
            const float* lmd = landm_data + ((size_t)b * P + p) * 10;
            const float* lm  = targets + ((size_t)b * T + bt) * 15 + 4;
            float pw = px2[j] - px1[j], ph = py2[j] - py1[j];
            float pcx = (px1[j] + px2[j]) * 0.5f, pcy = (py1[j] + py2[j]) * 0.5f;
            float sx = frcp(0.1f * pw), sy = frcp(0.1f * ph);
            float s = 0.0f;
            #pragma unroll
            for (int k = 0; k < 5; k++) {
                float gx = (lm[2 * k]     - pcx) * sx;
                float gy = (lm[2 * k + 1] - pcy) * sy;
                s += sl1(lmd[2 * k] - gx) + sl1(lmd[2 * k + 1] - gy);
            }
            llm_s += s;
            np1_s++;
        }
    }
    if (p0 + PPT <= P) {
        *(float4*)&rank_loss[(size_t)b * P + p0] = make_float4(rl[0], rl[1], rl[2], rl[3]);
    } else {
        for (int j = 0; j < PPT; j++)
            if (p0 + j < P) rank_loss[(size_t)b * P + p0 + j] = rl[j];
    }

    if (np_s)  { atomicAdd(&s_ll, ll_s); atomicAdd(&s_cep, cep_s); atomicAdd(&s_np, np_s); }
    if (np1_s) { atomicAdd(&s_llm, llm_s); atomicAdd(&s_np1, np1_s); }
    __syncthreads();
    if (tid == 0) {
        if (s_np)  { atomicAdd(&num_pos[b], s_np); atomicAdd(&acc[0], s_ll); atomicAdd(&acc[2], s_cep); }
        if (s_np1) { atomicAdd(total_pos1, s_np1); atomicAdd(&acc[1], s_llm); }
    }
    // flush coarse histogram (few hundred nonzero buckets per block)
    for (int i = tid; i < HB; i += blockDim.x) {
        int v = s_hist[i];
        if (v) atomicAdd(&ghist[(size_t)b * HB + i], v);
    }
}

// ---- single-wave digit select over nb (<=256) buckets in LDS hist ----
// On entry *s_r = rank (1-based, from largest). Picks digit d with
// ge(d) >= r > ge(d+1); writes *s_dig = d and *s_r = r - ge(d+1).
__device__ __forceinline__ void select_digit(const int* hist, int nb, int tid,
                                             int* s_dig, int* s_r) {
    if (tid < 64) {
        int lane = tid;
        int per  = (nb >= 64) ? (nb >> 6) : 1;
        int base = lane * per;
        int v[4]; int s = 0;
        #pragma unroll
        for (int j = 0; j < 4; j++) {
            int idx = base + j;
            int h = (j < per && idx < nb) ? hist[idx] : 0;
            v[j] = h; s += h;
        }
        int sfx = s;
        for (int off = 1; off < 64; off <<= 1) {
            int t = __shfl_down(sfx, off);
            if (lane + off < 64) sfx += t;
        }
        int r  = *s_r;
        int ge = sfx;
        #pragma unroll
        for (int j = 0; j < 4; j++) {
            int gen = ge - v[j];
            int d   = base + j;
            if (j < per && d < nb && ge >= r && gen < r) { *s_dig = d; *s_r = r - gen; }
            ge = gen;
        }
    }
}

// ---------------- K4: per-batch sum of top-K rank_loss --------------------------------
// Coarse 11-bit bucket from precomputed ghist; ONE full scan (S_hi + compact boundary
// bucket to LDS); low 20 bits resolved on the LDS list. Exact.
__global__ void topk_kernel(const float* __restrict__ rank_loss,
                            const int* __restrict__ num_pos,
                            const int* __restrict__ ghist,
                            int P, float* __restrict__ acc) {
    int b    = blockIdx.x;
    int tid  = threadIdx.x;
    int lane = tid & 63;
    int wv   = tid >> 6;
    long long Kll = (long long)num_pos[b] * NEGPOS;
    int K = (Kll > P - 1) ? (P - 1) : (int)Kll;
    if (K <= 0) return;

    __shared__ int   hist[256];
    __shared__ float slist[CAP];
    __shared__ int   s_d1, s_r, s_cnt1, s_lcnt, s_dig;
    __shared__ float s_S[16];
    __shared__ int   s_C[16];
    __shared__ float s_Shi;
    __shared__ int   s_Chi;

    const int* gh = ghist + (size_t)b * HB;

    // --- step A: pick coarse bucket d1 from ghist (single wave) ---
    if (wv == 0) {
        if (lane == 0) { s_lcnt = 0; s_r = K; }
        int base = lane * 32;                 // HB/64 buckets per lane
        int v[32]; int s = 0;
        #pragma unroll
        for (int j = 0; j < 32; j++) { v[j] = gh[base + j]; s += v[j]; }
        int sfx = s;
        for (int off = 1; off < 64; off <<= 1) {
            int t = __shfl_down(sfx, off);
            if (lane + off < 64) sfx += t;
        }
        int ge = sfx;                          // ge(base)
        #pragma unroll
        for (int j = 0; j < 32; j++) {
            int gen = ge - v[j];
            if (ge >= K && gen < K) { s_d1 = base + j; s_r = K - gen; s_cnt1 = v[j]; }
            ge = gen;
        }
    }
    __syncthreads();
    int d1 = s_d1, cnt1 = s_cnt1;
    bool fastpath = (cnt1 <= CAP);
    unsigned hi_lim = ((unsigned)(d1 + 1)) << 20;   // u >= hi_lim <=> bucket > d1

    const float4* v4 = (const float4*)(rank_loss + (size_t)b * P);
    int n4 = P >> 2;
    unsigned pmask = 0u, pval = 0u;           // low-20-bit prefix state
    const int shf[3] = {12, 4, 0};
    const int nbk[3] = {256, 256, 16};

    if (fastpath) {
        // --- step B: one full scan: S_hi/C_hi + compact bucket==d1 into LDS ---
        float Shi = 0.f; int Chi = 0;
        for (int i = tid; i < n4; i += blockDim.x) {
            float4 x = v4[i];
            float xs[4] = {x.x, x.y, x.z, x.w};
            #pragma unroll
            for (int k = 0; k < 4; k++) {
                unsigned u = __float_as_uint(xs[k]);
                if (u >= hi_lim) { Shi += xs[k]; Chi++; }
                bool m = ((u >> 20) == (unsigned)d1);
                unsigned long long mk = __ballot(m);
                if (m) {
                    int leader = __ffsll((long long)mk) - 1;
                    int base = 0;
                    if (lane == leader) base = atomicAdd(&s_lcnt, __popcll(mk));
                    base = __shfl(base, leader);
                    int ofs = __popcll(mk & (((unsigned long long)1 << lane) - 1ull));
                    slist[base + ofs] = xs[k];
                }
            }
        }
        for (int off = 32; off; off >>= 1) {
            Shi += __shfl_down(Shi, off);
            Chi += __shfl_down(Chi, off);
        }
        if (lane == 0) { s_S[wv] = Shi; s_C[wv] = Chi; }
        __syncthreads();
        if (tid == 0) {
            float S = 0.f; int C = 0;
            for (int i = 0; i < 16; i++) { S += s_S[i]; C += s_C[i]; }
            s_Shi = S; s_Chi = C;
        }
        __syncthreads();
        int lc = s_lcnt;   // == cnt1

        // --- step C: resolve low 20 bits on LDS list (3 tiny radix passes) ---
        for (int ps = 0; ps < 3; ps++) {
            int sh = shf[ps]; unsigned wm = (unsigned)(nbk[ps] - 1);
            if (tid < 256) hist[tid] = 0;
            __syncthreads();
            for (int i = tid; i < lc; i += blockDim.x) {
                unsigned u = __float_as_uint(slist[i]);
                if ((u & pmask) == pval) atomicAdd(&hist[(u >> sh) & wm], 1);
            }
            __syncthreads();
            select_digit(hist, nbk[ps], tid, &s_dig, &s_r);
            __syncthreads();
            pval  |= ((unsigned)s_dig) << sh;
            pmask |= wm << sh;
        }
        float tau = __uint_as_float((((unsigned)d1) << 20) | pval);

        // --- final: sum/count of list elements > tau ---
        float S = 0.f; int C = 0;
        for (int i = tid; i < lc; i += blockDim.x) {
            float x = slist[i];
            if (x > tau) { S += x; C++; }
        }
        for (int off = 32; off; off >>= 1) {
            S += __shfl_down(S, off);
            C += __shfl_down(C, off);
        }
        if (lane == 0) { s_S[wv] = S; s_C[wv] = C; }
        __syncthreads();
        if (tid == 0) {
            float St = s_Shi; int Ct = s_Chi;
            for (int i = 0; i < 16; i++) { St += s_S[i]; Ct += s_C[i]; }
            atomicAdd(&acc[3], St + (float)(K - Ct) * tau);
        }
    } else {
        // --- fallback (pathological bucket > CAP): filtered full scans ---
        for (int ps = 0; ps < 3; ps++) {
            int sh = shf[ps]; unsigned wm = (unsigned)(nbk[ps] - 1);
            if (tid < 256) hist[tid] = 0;
            __syncthreads();
            for (int i = tid; i < n4; i += blockDim.x) {
                float4 x = v4[i];
                float xs[4] = {x.x, x.y, x.z, x.w};
                #pragma unroll
                for (int k = 0; k < 4; k++) {
                    unsigned u = __float_as_uint(xs[k]);
                    if ((u >> 20) == (unsigned)d1 && (u & pmask) == pval)
                        atomicAdd(&hist[(u >> sh) & wm], 1);
                }
            }
            __syncthreads();
            select_digit(hist, nbk[ps], tid, &s_dig, &s_r);
            __syncthreads();
            pval  |= ((unsigned)s_dig) << sh;
            pmask |= wm << sh;
        }
        float tau = __uint_as_float((((unsigned)d1) << 20) | pval);
        float S = 0.f; int C = 0;
        for (int i = tid; i < n4; i += blockDim.x) {
            float4 x = v4[i];
            float xs[4] = {x.x, x.y, x.z, x.w};
            #pragma unroll
            for (int k = 0; k < 4; k++)
                if (xs[k] > tau) { S += xs[k]; C++; }
        }
        for (int off = 32; off; off >>= 1) {
            S += __shfl_down(S, off);
            C += __shfl_down(C, off);
        }
        if (lane == 0) { s_S[wv] = S; s_C[wv] = C; }
        __syncthreads();
        if (tid == 0) {
            float St = 0.f; int Ct = 0;
            for (int i = 0; i < 16; i++) { St += s_S[i]; Ct += s_C[i]; }
            atomicAdd(&acc[3], St + (float)(K - Ct) * tau);
        }
    }
}

// ---------------- K5: finalize -------------------------------------------------------
__global__ void finalize_kernel(const int* __restrict__ num_pos,
                                const int* __restrict__ total_pos1,
                                const float* __restrict__ acc,
                                int B, float* __restrict__ out) {
    int tp = 0;
    for (int b = 0; b < B; b++) tp += num_pos[b];
    float N  = fmaxf((float)tp, 1.0f);
    float N1 = fmaxf((float)(*total_pos1), 1.0f);
    out[0] = acc[0] / N;                 // loss_l / N
    out[1] = (acc[2] + acc[3]) / N;      // loss_c / N
    out[2] = acc[1] / N1;                // loss_landm / N1
}

extern "C" void kernel_launch(void* const* d_in, const int* in_sizes, int n_in,
                              void* d_out, int out_size, void* d_ws, size_t ws_size,
                              hipStream_t stream) {
    const float* loc_data   = (const float*)d_in[0];
    const float* conf_data  = (const float*)d_in[1];
    const float* landm_data = (const float*)d_in[2];
    const float* priors     = (const float*)d_in[3];
    const float* targets    = (const float*)d_in[4];
    float* out = (float*)d_out;

    int P  = in_sizes[3] / 4;
    int BP = in_sizes[0] / 4;
    int B  = BP / P;
    int T  = in_sizes[4] / (B * 15);
    int BT = B * T;

    char* ws = (char*)d_ws;
    float* rank_loss = (float*)ws;
    size_t off = (size_t)B * P * sizeof(float);
    // zeroed region starts here
    int* ghist      = (int*)(ws + off); off += (size_t)B * HB * sizeof(int);
    unsigned long long* keys = (unsigned long long*)(ws + off); off += (size_t)BT * sizeof(unsigned long long);
    int* num_pos    = (int*)(ws + off); off += (size_t)B * sizeof(int);
    int* total_pos1 = (int*)(ws + off); off += sizeof(int);
    float* acc      = (float*)(ws + off); off += 4 * sizeof(float);

    size_t zbytes = (size_t)((char*)(acc + 4) - (char*)ghist);
    hipMemsetAsync(ghist, 0, zbytes, stream);

    // K2: split-K best-prior, 4 targets per wave.
    int waves   = NCHUNK * ((BT + TPW - 1) / TPW);
    int blocks2 = (waves + 3) / 4;
    best_prior_partial_kernel<<<blocks2, 256, 0, stream>>>(priors, targets, P, BT, keys);

    // K3: match + per-prior losses + coarse rank_loss histogram.
    dim3 g3((P + 256 * PPT - 1) / (256 * PPT), B);
    match_loss_kernel<<<g3, 256, 0, stream>>>(priors, targets, loc_data, conf_data,
                                              landm_data, keys, P, T,
                                              rank_loss, ghist, num_pos, total_pos1, acc);

    // K4: top-K sum, one full scan + LDS-local refinement.
    topk_kernel<<<B, 1024, 0, stream>>>(rank_loss, num_pos, ghist, P, acc);

    finalize_kernel<<<1, 1, 0, stream>>>(num_pos, total_pos1, acc, B, out);
}